// Round 5
// baseline (181.560 us; speedup 1.0000x reference)
//
#include <hip/hip_runtime.h>
#include <math.h>

// GraspCVAE loss, MI355X — round 5.
// Harness insight (round 4 rocprof): the 268 MB d_ws 0xAA re-poison costs a
// fixed ~41 us per timed iteration (top dispatch, 82% HBM peak). Controllable
// budget is only ~80 us. So this round fuses EVERYTHING into one worker
// kernel (plus a ~2 us sentinel/counter init):
//  * obj->hand NN: j-split 4, packed-index keys (idx in low-10 mantissa bits),
//    monotone-mapped u32 atomicMin combine across splits.
//  * hand->obj NN: 12 obj chunks, mono-mapped atomicMin per hand point.
//  * last split block per (b,tile) finalizes obj points (prior NN, normals,
//    penetr/contact/consistency/loss_o) inline; last chunk block per b
//    finalizes loss_h + recon_loss + KLD; last of 128 contributors writes out.
// All cross-block communication via device-scope atomics (XCD-safe); no
// spin-waits (no co-residency assumption). 2 dispatches total.

#define NB 32
#define NH 778
#define NO 3000
#define NZ 64
#define NP 204

#define P_OBJ 4
#define OBJ_PTS 1024
#define OBJ_TILES 3                  // ceil(3000/1024)
#define JSPLIT 4
#define JCH 195                      // ceil(778/4)
#define HC 12                        // hand-side obj chunks
#define HCS 250                      // 3000/12
#define OBJ_BLKS (NB * OBJ_TILES * JSPLIT)   // 384
#define HAND_BLKS (NB * HC)                  // 384
#define NKEY (NB * NO)               // 96000
#define NHT  (NB * NH)               // 24896
#define NCNT (1 + NB * OBJ_TILES + NB)       // 129 counters
#define N_CONTRIB (NB * OBJ_TILES + NB)      // 128
#define NSENT (2 * NKEY + 2 * NHT)           // sentinel words

typedef unsigned int uint32;

__device__ __constant__ int c_prior[NP] = {
  697,698,699,700,712,713,714,715,737,738,739,740,741,743,744,745,746,748,749,750,
  753,754,755,756,757,758,759,760,761,762,763,764,765,766,767,768,
  46,47,48,49,164,165,166,167,194,195,223,237,238,280,281,298,301,317,320,323,
  324,325,326,327,328,329,330,331,332,333,340,341,342,343,344,345,346,347,348,349,
  350,351,352,353,354,355,
  356,357,358,359,375,376,386,387,396,397,402,403,413,429,433,434,435,436,437,438,
  439,440,441,442,443,444,452,453,454,455,456,459,460,461,462,463,464,465,466,467,
  468,469,470,471,484,485,486,496,497,506,507,513,514,524,545,546,547,548,549,550,
  551,552,553,555,563,564,565,566,567,570,572,573,574,575,576,577,578,
  580,581,582,583,600,601,602,614,615,624,625,630,631,641,663,664,665,666,667,668,
  670,672,680,681,682,683,684,686,687,688,689,690,691,692,693,694,695,
  73,96,98,99,772,774,775,777
};

__device__ inline float wave_sum(float v) {
  v += __shfl_down(v, 32);
  v += __shfl_down(v, 16);
  v += __shfl_down(v, 8);
  v += __shfl_down(v, 4);
  v += __shfl_down(v, 2);
  v += __shfl_down(v, 1);
  return v;
}

// index packed into low 10 mantissa bits; float order ~ (t, j) lexicographic
__device__ inline float packkey(float t, int j) {
  return __uint_as_float((__float_as_uint(t) & 0xFFFFFC00u) | (uint32)j);
}
// monotone float->uint map (handles negatives) for u32 atomicMin
__device__ inline uint32 mono(float f) {
  uint32 b = __float_as_uint(f);
  return b ^ (uint32)(((int)b >> 31) | 0x80000000);
}
__device__ inline uint32 unmono(uint32 u) {
  return u ^ ((u & 0x80000000u) ? 0x80000000u : 0xFFFFFFFFu);
}
__device__ inline float aread(float* p) {        // coherent device-scope read
  return atomicAdd(p, 0.0f);
}
__device__ inline uint32 areadu(uint32* p) {
  return atomicOr(p, 0u);
}

// accs: 0 penetr, 1 npts, 2 contact, 3 consist, 4 loss_o, 5 loss_h, 6 recon_sq, 7 kld
__global__ void init_k(float* __restrict__ accs, int* __restrict__ cnts,
                       uint32* __restrict__ sent) {
  int t = blockIdx.x * 256 + threadIdx.x;
  if (t < 16) accs[t] = 0.0f;
  if (t < NCNT) cnts[t] = 0;
  for (int i = t; i < NSENT; i += gridDim.x * 256) sent[i] = 0xFFFFFFFFu;
}

__device__ inline void final_combine(float* accs, float* out) {
  float a[8];
  #pragma unroll
  for (int q = 0; q < 8; ++q) a[q] = aread(&accs[q]);
  const float recon_loss = a[6] / (float)NB;
  const float kld = -0.5f * a[7] / (float)NB * 10.f;
  const float penetr = 100.f * a[0] / (float)NB;
  const float npts = a[1];
  const float contact = (npts > 0.f) ? (3000.f * a[2] / ((float)NB * npts)) : 0.f;
  const float consistency = -5.f * a[3] / (npts + 0.0001f);
  const float lossh = 35.f * (1.f - 0.005f) * (a[5] / (float)(NB * NH));
  const float losso = 30.f * (1.f - 0.005f) * (a[4] / (float)(NB * NO));
  out[0] = recon_loss + 0.1f * kld + 1000.f * penetr + 10.f * contact
         + 10.f * consistency + lossh + losso;
}

__global__ __launch_bounds__(256) void mega(
    const float* __restrict__ recon, const float* __restrict__ gt,
    const float* __restrict__ rnorm, const float* __restrict__ gnorm,
    const float* __restrict__ obj,
    const float* __restrict__ mean, const float* __restrict__ logv,
    const float* __restrict__ vw,
    uint32* __restrict__ keyR, uint32* __restrict__ keyG,
    uint32* __restrict__ minHR, uint32* __restrict__ minHG,
    float* __restrict__ accs, int* __restrict__ gcnt,
    int* __restrict__ cntObj, int* __restrict__ cntHand,
    float* __restrict__ out)
{
  __shared__ float4 shA[HCS];    // 250: sR(195) / sO(250)
  __shared__ float4 shB[NP];     // 204: sG(195) / prior(204)
  __shared__ float red[4][5];
  __shared__ int flag;
  const int bid = blockIdx.x;
  const int tid = threadIdx.x;
  const int lane = tid & 63, wv = tid >> 6;

  if (bid < OBJ_BLKS) {
    // ================= obj -> hand NN (split) =================
    const int b     = bid / (OBJ_TILES * JSPLIT);
    const int rem   = bid % (OBJ_TILES * JSPLIT);
    const int tile  = rem / JSPLIT;
    const int split = rem % JSPLIT;
    const int jbase = split * JCH;
    const int jcnt  = (NH - jbase < JCH) ? (NH - jbase) : JCH;

    for (int i = tid; i < jcnt; i += 256) {
      const float* p = recon + ((size_t)b * NH + jbase + i) * 3;
      float x = p[0], y = p[1], z = p[2];
      shA[i] = make_float4(x, y, z, x*x + y*y + z*z);
      const float* q = gt + ((size_t)b * NH + jbase + i) * 3;
      float gx = q[0], gy = q[1], gz = q[2];
      shB[i] = make_float4(gx, gy, gz, gx*gx + gy*gy + gz*gz);
    }
    __syncthreads();

    float nx[P_OBJ], ny[P_OBJ], nz[P_OBJ];
    int ob[P_OBJ]; bool val[P_OBJ];
    #pragma unroll
    for (int m = 0; m < P_OBJ; ++m) {
      int o = tile * OBJ_PTS + m * 256 + tid;
      ob[m] = o; val[m] = (o < NO);
      float x = 0.f, y = 0.f, z = 0.f;
      if (val[m]) {
        const float* op = obj + ((size_t)b * NO + o) * 3;
        x = op[0]; y = op[1]; z = op[2];
      }
      nx[m] = -2.f * x; ny[m] = -2.f * y; nz[m] = -2.f * z;
    }

    float bR[P_OBJ], bG[P_OBJ];
    #pragma unroll
    for (int m = 0; m < P_OBJ; ++m) { bR[m] = 3.4e38f; bG[m] = 3.4e38f; }

    int i = 0;
    for (; i + 1 < jcnt; i += 2) {
      float4 h0 = shA[i], h1 = shA[i + 1];
      #pragma unroll
      for (int m = 0; m < P_OBJ; ++m) {
        float t0 = fmaf(nx[m], h0.x, h0.w); t0 = fmaf(ny[m], h0.y, t0); t0 = fmaf(nz[m], h0.z, t0);
        float t1 = fmaf(nx[m], h1.x, h1.w); t1 = fmaf(ny[m], h1.y, t1); t1 = fmaf(nz[m], h1.z, t1);
        bR[m] = fminf(bR[m], fminf(packkey(t0, jbase + i), packkey(t1, jbase + i + 1)));
      }
      float4 g0 = shB[i], g1 = shB[i + 1];
      #pragma unroll
      for (int m = 0; m < P_OBJ; ++m) {
        float t0 = fmaf(nx[m], g0.x, g0.w); t0 = fmaf(ny[m], g0.y, t0); t0 = fmaf(nz[m], g0.z, t0);
        float t1 = fmaf(nx[m], g1.x, g1.w); t1 = fmaf(ny[m], g1.y, t1); t1 = fmaf(nz[m], g1.z, t1);
        bG[m] = fminf(bG[m], fminf(packkey(t0, jbase + i), packkey(t1, jbase + i + 1)));
      }
    }
    if (i < jcnt) {
      float4 h0 = shA[i];
      float4 g0 = shB[i];
      #pragma unroll
      for (int m = 0; m < P_OBJ; ++m) {
        float t0 = fmaf(nx[m], h0.x, h0.w); t0 = fmaf(ny[m], h0.y, t0); t0 = fmaf(nz[m], h0.z, t0);
        bR[m] = fminf(bR[m], packkey(t0, jbase + i));
        float u0 = fmaf(nx[m], g0.x, g0.w); u0 = fmaf(ny[m], g0.y, u0); u0 = fmaf(nz[m], g0.z, u0);
        bG[m] = fminf(bG[m], packkey(u0, jbase + i));
      }
    }

    #pragma unroll
    for (int m = 0; m < P_OBJ; ++m) {
      if (!val[m]) continue;
      const uint32 base = (uint32)(b * NO + ob[m]);
      atomicMin(&keyR[base], mono(bR[m]));
      atomicMin(&keyG[base], mono(bG[m]));
    }
    __threadfence();
    __syncthreads();
    if (tid == 0)
      flag = (atomicAdd(&cntObj[b * OBJ_TILES + tile], 1) == JSPLIT - 1) ? 1 : 0;
    __syncthreads();
    if (!flag) return;

    // ============ finalize this (b,tile): last split block ============
    if (tid < NP) {
      int j = c_prior[tid];
      const float* p = recon + ((size_t)b * NH + j) * 3;
      float x = p[0], y = p[1], z = p[2];
      shB[tid] = make_float4(x, y, z, x*x + y*y + z*z);
    }
    __syncthreads();
    if (tid == 0) __threadfence();   // acquire after counter
    float penetr = 0.f, nptsv = 0.f, contactv = 0.f, consistv = 0.f, lossov = 0.f;
    #pragma unroll
    for (int m = 0; m < P_OBJ; ++m) {
      if (!val[m]) continue;
      const float ox = -0.5f * nx[m], oy = -0.5f * ny[m], oz = -0.5f * nz[m];
      const float o2 = ox*ox + oy*oy + oz*oz;
      const uint32 base = (uint32)(b * NO + ob[m]);
      uint32 kRb = unmono(areadu(&keyR[base]));
      uint32 kGb = unmono(areadu(&keyG[base]));
      int idxR = (int)(kRb & 0x3FFu), idxG = (int)(kGb & 0x3FFu);
      float d2R = fmaxf(__uint_as_float(kRb & 0xFFFFFC00u) + o2, 0.f);
      float d2G = fmaxf(__uint_as_float(kGb & 0xFFFFFC00u) + o2, 0.f);

      float bP = 3.4e38f;
      for (int k = 0; k < NP; k += 2) {
        float4 h0 = shB[k], h1 = shB[k + 1];
        float t0 = fmaf(nx[m], h0.x, h0.w); t0 = fmaf(ny[m], h0.y, t0); t0 = fmaf(nz[m], h0.z, t0);
        float t1 = fmaf(nx[m], h1.x, h1.w); t1 = fmaf(ny[m], h1.y, t1); t1 = fmaf(nz[m], h1.z, t1);
        bP = fminf(bP, fminf(t0, t1));
      }
      float d2P = fmaxf(bP + o2, 0.f);

      const float* hR = recon + ((size_t)b * NH + idxR) * 3;
      const float* nR = rnorm + ((size_t)b * NH + idxR) * 3;
      float dotR = (ox - hR[0]) * nR[0] + (oy - hR[1]) * nR[1] + (oz - hR[2]) * nR[2];
      const float* hG = gt + ((size_t)b * NH + idxG) * 3;
      const float* nG = gnorm + ((size_t)b * NH + idxG) * 3;
      float dotG = (ox - hG[0]) * nG[0] + (oy - hG[1]) * nG[1] + (oz - hG[2]) * nG[2];

      float sgnR = (dotR > 0.f) ? 1.f : ((dotR < 0.f) ? -1.f : 0.f);
      float sgnG = (dotG > 0.f) ? 1.f : ((dotG < 0.f) ? -1.f : 0.f);
      float sR_ = sqrtf(d2R), sG_ = sqrtf(d2G);
      float o2h = sR_ * sgnR, o2hg = sG_ * sgnG;

      bool interior = dotR < 0.f;
      bool cmap = sG_ < 0.005f;
      bool rcmap = sR_ < 0.005f;

      penetr   += interior ? d2R : 0.f;
      nptsv    += cmap ? 1.f : 0.f;
      contactv += cmap ? d2P : 0.f;
      consistv += (cmap && rcmap) ? 1.f : 0.f;
      float w = (o2h < 0.f) ? 1.5f
              : (((o2hg < 0.01f) && (o2hg > -0.005f)) ? 1.f : 0.1f);
      lossov += fabsf(o2h - o2hg) * w;
    }

    float vals[5] = {penetr, nptsv, contactv, consistv, lossov};
    #pragma unroll
    for (int q = 0; q < 5; ++q) {
      float s = wave_sum(vals[q]);
      if (lane == 0) red[wv][q] = s;
    }
    __syncthreads();
    if (tid < 5) {
      float s = red[0][tid] + red[1][tid] + red[2][tid] + red[3][tid];
      atomicAdd(&accs[tid], s);
    }
    __threadfence();
    __syncthreads();
    if (tid == 0) {
      if (atomicAdd(gcnt, 1) == N_CONTRIB - 1) final_combine(accs, out);
    }
  } else {
    // ================= hand -> obj NN (chunk) =================
    const int bid2 = bid - OBJ_BLKS;
    const int oc = bid2 % HC;
    const int b  = bid2 / HC;

    const float* Ob = obj + ((size_t)b * NO + oc * HCS) * 3;
    for (int i2 = tid; i2 < HCS; i2 += 256) {
      float x = Ob[3*i2], y = Ob[3*i2+1], z = Ob[3*i2+2];
      shA[i2] = make_float4(x, y, z, x*x + y*y + z*z);
    }
    __syncthreads();

    float nrx[4], nry[4], nrz[4];
    float ngx[4], ngy[4], ngz[4];
    bool val[4];
    #pragma unroll
    for (int m = 0; m < 4; ++m) {
      int j = m * 256 + tid;
      val[m] = (j < NH);
      float rx = 0.f, ry = 0.f, rz = 0.f, gx = 0.f, gy = 0.f, gz = 0.f;
      if (val[m]) {
        const float* rp = recon + ((size_t)b * NH + j) * 3;
        const float* gp = gt    + ((size_t)b * NH + j) * 3;
        rx = rp[0]; ry = rp[1]; rz = rp[2];
        gx = gp[0]; gy = gp[1]; gz = gp[2];
      }
      nrx[m] = -2.f*rx; nry[m] = -2.f*ry; nrz[m] = -2.f*rz;
      ngx[m] = -2.f*gx; ngy[m] = -2.f*gy; ngz[m] = -2.f*gz;
    }

    float mR[4], mG[4];
    #pragma unroll
    for (int m = 0; m < 4; ++m) { mR[m] = 3.4e38f; mG[m] = 3.4e38f; }

    for (int k = 0; k < HCS; k += 2) {
      float4 o0 = shA[k], o1 = shA[k + 1];
      #pragma unroll
      for (int m = 0; m < 4; ++m) {
        float t0 = fmaf(nrx[m], o0.x, o0.w); t0 = fmaf(nry[m], o0.y, t0); t0 = fmaf(nrz[m], o0.z, t0);
        float t1 = fmaf(nrx[m], o1.x, o1.w); t1 = fmaf(nry[m], o1.y, t1); t1 = fmaf(nrz[m], o1.z, t1);
        mR[m] = fminf(mR[m], fminf(t0, t1));
        float u0 = fmaf(ngx[m], o0.x, o0.w); u0 = fmaf(ngy[m], o0.y, u0); u0 = fmaf(ngz[m], o0.z, u0);
        float u1 = fmaf(ngx[m], o1.x, o1.w); u1 = fmaf(ngy[m], o1.y, u1); u1 = fmaf(ngz[m], o1.z, u1);
        mG[m] = fminf(mG[m], fminf(u0, u1));
      }
    }

    #pragma unroll
    for (int m = 0; m < 4; ++m) {
      if (!val[m]) continue;
      int j = m * 256 + tid;
      const uint32 idx = (uint32)(b * NH + j);
      atomicMin(&minHR[idx], mono(mR[m]));
      atomicMin(&minHG[idx], mono(mG[m]));
    }
    __threadfence();
    __syncthreads();
    if (tid == 0)
      flag = (atomicAdd(&cntHand[b], 1) == HC - 1) ? 1 : 0;
    __syncthreads();
    if (!flag) return;

    // ============ finalize batch b: last chunk block ============
    if (tid == 0) __threadfence();
    float lossh = 0.f, rsum = 0.f, ksum = 0.f;
    #pragma unroll
    for (int m = 0; m < 4; ++m) {
      int j = m * 256 + tid;
      if (j >= NH) continue;
      const float* rp = recon + ((size_t)b * NH + j) * 3;
      const float* gp = gt    + ((size_t)b * NH + j) * 3;
      float rx = rp[0], ry = rp[1], rz = rp[2];
      float gx = gp[0], gy = gp[1], gz = gp[2];
      float d0 = rx - gx, d1 = ry - gy, d2 = rz - gz;
      rsum += d0*d0 + d1*d1 + d2*d2;

      float tR = __uint_as_float(unmono(areadu(&minHR[b * NH + j])));
      float tG = __uint_as_float(unmono(areadu(&minHG[b * NH + j])));
      float r2 = rx*rx + ry*ry + rz*rz;
      float g2 = gx*gx + gy*gy + gz*gz;
      float d2Rh = fmaxf(tR + r2, 0.f);
      float d2Gh = fmaxf(tG + g2, 0.f);
      lossh += fabsf(sqrtf(d2Rh) - sqrtf(d2Gh)) * powf(vw[j], 0.4f);
    }
    if (tid < NZ) {
      float mm = mean[b * NZ + tid], lv = logv[b * NZ + tid];
      ksum = 1.f + lv - mm * mm - expf(lv);
    }
    float vals[3] = {lossh, rsum, ksum};
    #pragma unroll
    for (int q = 0; q < 3; ++q) {
      float s = wave_sum(vals[q]);
      if (lane == 0) red[wv][q] = s;
    }
    __syncthreads();
    if (tid < 3) {
      float s = red[0][tid] + red[1][tid] + red[2][tid] + red[3][tid];
      atomicAdd(&accs[5 + tid], s);
    }
    __threadfence();
    __syncthreads();
    if (tid == 0) {
      if (atomicAdd(gcnt, 1) == N_CONTRIB - 1) final_combine(accs, out);
    }
  }
}

// =========================== PATH C (tiny ws fallback) ===========================
__global__ __launch_bounds__(256) void obj_mono(
    const float* __restrict__ recon, const float* __restrict__ gt,
    const float* __restrict__ rnorm, const float* __restrict__ gnorm,
    const float* __restrict__ obj, float* __restrict__ accs)
{
  __shared__ float4 sR[NH];
  __shared__ float4 sG[NH];
  __shared__ float red[4][5];
  const int b = blockIdx.x / 12;
  const int tile = blockIdx.x % 12;
  const int tid = threadIdx.x;
  for (int i = tid; i < NH; i += 256) {
    const float* p = recon + ((size_t)b * NH + i) * 3;
    float x = p[0], y = p[1], z = p[2];
    sR[i] = make_float4(x, y, z, x*x + y*y + z*z);
    const float* q = gt + ((size_t)b * NH + i) * 3;
    float gx = q[0], gy = q[1], gz = q[2];
    sG[i] = make_float4(gx, gy, gz, gx*gx + gy*gy + gz*gz);
  }
  __syncthreads();
  const int o = tile * 256 + tid;
  float penetr = 0.f, nptsv = 0.f, contactv = 0.f, consistv = 0.f, lossov = 0.f;
  if (o < NO) {
    const float* op = obj + ((size_t)b * NO + o) * 3;
    const float ox = op[0], oy = op[1], oz = op[2];
    const float nx = -2.f*ox, ny = -2.f*oy, nz = -2.f*oz;
    const float o2 = ox*ox + oy*oy + oz*oz;
    float bR = 3.4e38f, bG = 3.4e38f; int iR = 0, iG = 0;
    for (int i = 0; i < NH; ++i) {
      float4 h = sR[i];
      float t = fmaf(nx, h.x, h.w); t = fmaf(ny, h.y, t); t = fmaf(nz, h.z, t);
      if (t < bR) { bR = t; iR = i; }
      float4 g = sG[i];
      float u = fmaf(nx, g.x, g.w); u = fmaf(ny, g.y, u); u = fmaf(nz, g.z, u);
      if (u < bG) { bG = u; iG = i; }
    }
    float bP = 3.4e38f;
    for (int k = 0; k < NP; ++k) {
      float4 h = sR[c_prior[k]];
      float t = fmaf(nx, h.x, h.w); t = fmaf(ny, h.y, t); t = fmaf(nz, h.z, t);
      bP = fminf(bP, t);
    }
    float d2R = fmaxf(bR + o2, 0.f);
    float d2G = fmaxf(bG + o2, 0.f);
    float d2P = fmaxf(bP + o2, 0.f);
    float4 hR = sR[iR];
    const float* nR = rnorm + ((size_t)b * NH + iR) * 3;
    float dotR = (ox-hR.x)*nR[0] + (oy-hR.y)*nR[1] + (oz-hR.z)*nR[2];
    float4 hG = sG[iG];
    const float* nG = gnorm + ((size_t)b * NH + iG) * 3;
    float dotG = (ox-hG.x)*nG[0] + (oy-hG.y)*nG[1] + (oz-hG.z)*nG[2];
    float sgnR = (dotR > 0.f) ? 1.f : ((dotR < 0.f) ? -1.f : 0.f);
    float sgnG = (dotG > 0.f) ? 1.f : ((dotG < 0.f) ? -1.f : 0.f);
    float sR_ = sqrtf(d2R), sG_ = sqrtf(d2G);
    float o2h = sR_*sgnR, o2hg = sG_*sgnG;
    bool interior = dotR < 0.f;
    bool cmap = sG_ < 0.005f, rcmap = sR_ < 0.005f;
    penetr = interior ? d2R : 0.f;
    nptsv = cmap ? 1.f : 0.f;
    contactv = cmap ? d2P : 0.f;
    consistv = (cmap && rcmap) ? 1.f : 0.f;
    float w = (o2h < 0.f) ? 1.5f : (((o2hg < 0.01f) && (o2hg > -0.005f)) ? 1.f : 0.1f);
    lossov = fabsf(o2h - o2hg) * w;
  }
  float vals[5] = {penetr, nptsv, contactv, consistv, lossov};
  const int lane = tid & 63, wv = tid >> 6;
  for (int q = 0; q < 5; ++q) {
    float s = wave_sum(vals[q]);
    if (lane == 0) red[wv][q] = s;
  }
  __syncthreads();
  if (tid < 5) {
    float s = red[0][tid] + red[1][tid] + red[2][tid] + red[3][tid];
    atomicAdd(&accs[tid], s);
  }
}

__global__ __launch_bounds__(256) void hand_full(
    const float* __restrict__ recon, const float* __restrict__ gt,
    const float* __restrict__ obj, const float* __restrict__ vw,
    float* __restrict__ accs)
{
  __shared__ float4 sO[500];
  __shared__ float red[4];
  const int b = blockIdx.x >> 2;
  const int j = ((blockIdx.x & 3) << 8) + threadIdx.x;
  const bool valid = j < NH;
  float rx=0,ry=0,rz=0,gx=0,gy=0,gz=0;
  if (valid) {
    const float* rp = recon + ((size_t)b * NH + j) * 3;
    const float* gp = gt + ((size_t)b * NH + j) * 3;
    rx=rp[0];ry=rp[1];rz=rp[2]; gx=gp[0];gy=gp[1];gz=gp[2];
  }
  const float nrx=-2.f*rx, nry=-2.f*ry, nrz=-2.f*rz;
  const float ngx=-2.f*gx, ngy=-2.f*gy, ngz=-2.f*gz;
  const float r2 = rx*rx+ry*ry+rz*rz, g2 = gx*gx+gy*gy+gz*gz;
  float mR = 3.4e38f, mG = 3.4e38f;
  for (int oc = 0; oc < 6; ++oc) {
    __syncthreads();
    const float* Ob = obj + ((size_t)b * NO + oc * 500) * 3;
    for (int i = threadIdx.x; i < 500; i += 256) {
      float x = Ob[3*i], y = Ob[3*i+1], z = Ob[3*i+2];
      sO[i] = make_float4(x, y, z, x*x + y*y + z*z);
    }
    __syncthreads();
    if (valid) {
      for (int k = 0; k < 500; ++k) {
        float4 o4 = sO[k];
        float t = fmaf(nrx,o4.x,o4.w); t = fmaf(nry,o4.y,t); t = fmaf(nrz,o4.z,t);
        mR = fminf(mR, t);
        float u = fmaf(ngx,o4.x,o4.w); u = fmaf(ngy,o4.y,u); u = fmaf(ngz,o4.z,u);
        mG = fminf(mG, u);
      }
    }
  }
  float lossh = valid ? fabsf(sqrtf(fmaxf(mR+r2,0.f)) - sqrtf(fmaxf(mG+g2,0.f))) * powf(vw[j], 0.4f) : 0.f;
  const int lane = threadIdx.x & 63, wv = threadIdx.x >> 6;
  float s = wave_sum(lossh);
  if (lane == 0) red[wv] = s;
  __syncthreads();
  if (threadIdx.x == 0) atomicAdd(&accs[5], red[0]+red[1]+red[2]+red[3]);
}

__global__ __launch_bounds__(256) void tail_nomins(
    const float* __restrict__ recon, const float* __restrict__ gt,
    const float* __restrict__ mean, const float* __restrict__ logv,
    float* __restrict__ accs)
{
  __shared__ float red[4][2];
  const int t = blockIdx.x * 256 + threadIdx.x;
  float rsum = 0.f, ksum = 0.f;
  if (t < NB * NH) {
    const float* rp = recon + (size_t)t * 3;
    const float* gp = gt + (size_t)t * 3;
    float d0 = rp[0]-gp[0], d1 = rp[1]-gp[1], d2 = rp[2]-gp[2];
    rsum = d0*d0 + d1*d1 + d2*d2;
  }
  if (t < NB * NZ) {
    float m = mean[t], lv = logv[t];
    ksum = 1.f + lv - m*m - expf(lv);
  }
  float vals[2] = {rsum, ksum};
  const int lane = threadIdx.x & 63, wv = threadIdx.x >> 6;
  for (int q = 0; q < 2; ++q) {
    float s = wave_sum(vals[q]);
    if (lane == 0) red[wv][q] = s;
  }
  __syncthreads();
  if (threadIdx.x < 2) {
    float s = red[0][threadIdx.x] + red[1][threadIdx.x] + red[2][threadIdx.x] + red[3][threadIdx.x];
    atomicAdd(&accs[6 + threadIdx.x], s);
  }
}

__global__ void init_small(float* accs) {
  int t = threadIdx.x;
  if (t < 8) accs[t] = 0.0f;
}

__global__ void final_fb(const float* __restrict__ a, float* __restrict__ out) {
  const float recon_loss = a[6] / (float)NB;
  const float kld = -0.5f * a[7] / (float)NB * 10.f;
  const float penetr = 100.f * a[0] / (float)NB;
  const float npts = a[1];
  const float contact = (npts > 0.f) ? (3000.f * a[2] / ((float)NB * npts)) : 0.f;
  const float consistency = -5.f * a[3] / (npts + 0.0001f);
  const float lossh = 35.f * (1.f - 0.005f) * (a[5] / (float)(NB * NH));
  const float losso = 30.f * (1.f - 0.005f) * (a[4] / (float)(NB * NO));
  out[0] = recon_loss + 0.1f*kld + 1000.f*penetr + 10.f*contact + 10.f*consistency + lossh + losso;
}

extern "C" void kernel_launch(void* const* d_in, const int* in_sizes, int n_in,
                              void* d_out, int out_size, void* d_ws, size_t ws_size,
                              hipStream_t stream) {
  const float* recon = (const float*)d_in[0];
  const float* gt    = (const float*)d_in[1];
  const float* rnorm = (const float*)d_in[2];
  const float* gnorm = (const float*)d_in[3];
  const float* obj   = (const float*)d_in[4];
  const float* mean  = (const float*)d_in[5];
  const float* logv  = (const float*)d_in[6];
  const float* vw    = (const float*)d_in[7];
  float* out = (float*)d_out;

  // ws layout (PATH A): accs[16]f | gcnt+cntObj+cntHand (129 i32) | pad to 1KB |
  //                     keyR[96000] keyG[96000] minHR[24896] minHG[24896] (u32)
  float* accs = (float*)d_ws;
  int* gcnt = (int*)((char*)d_ws + 64);
  int* cntObj = gcnt + 1;
  int* cntHand = cntObj + NB * OBJ_TILES;
  uint32* keyR = (uint32*)((char*)d_ws + 1024);
  uint32* keyG = keyR + NKEY;
  uint32* minHR = keyG + NKEY;
  uint32* minHG = minHR + NHT;
  const size_t neededA = 1024 + (size_t)NSENT * 4;

  if (ws_size >= neededA) {
    init_k<<<120, 256, 0, stream>>>(accs, gcnt, keyR);
    mega<<<OBJ_BLKS + HAND_BLKS, 256, 0, stream>>>(
        recon, gt, rnorm, gnorm, obj, mean, logv, vw,
        keyR, keyG, minHR, minHG, accs, gcnt, cntObj, cntHand, out);
  } else {
    init_small<<<1, 64, 0, stream>>>(accs);
    obj_mono<<<NB * 12, 256, 0, stream>>>(recon, gt, rnorm, gnorm, obj, accs);
    hand_full<<<NB * 4, 256, 0, stream>>>(recon, gt, obj, vw, accs);
    tail_nomins<<<(NB * NH + 255) / 256, 256, 0, stream>>>(recon, gt, mean, logv, accs);
    final_fb<<<1, 1, 0, stream>>>(accs, out);
  }
}